// Round 2
// baseline (338.790 us; speedup 1.0000x reference)
//
#include <hip/hip_runtime.h>

typedef _Float16 f16;
typedef _Float16 f16x8 __attribute__((ext_vector_type(8)));
typedef float    f32x4 __attribute__((ext_vector_type(4)));

#define MFMA16(A, B, C) __builtin_amdgcn_mfma_f32_16x16x32_f16((A), (B), (C), 0, 0, 0)

static constexpr int kB = 4, kN = 2048, kH = 8, kD = 64, kDM = 512;
static constexpr int kM = kB * kN;  // 8192

// Workspace layout (bytes). Total = 44,040,192 B (~42 MB).
static constexpr size_t OFF_XH  = 0;                       // X fp16      [8192][512]  8 MB
static constexpr size_t OFF_WQT = 8388608;                 // Wq^T fp16   [512][512]   512 KB
static constexpr size_t OFF_WKT = OFF_WQT + 524288;
static constexpr size_t OFF_WVT = OFF_WKT + 524288;
static constexpr size_t OFF_WOT = OFF_WVT + 524288;
static constexpr size_t OFF_QH  = OFF_WOT + 524288;        // Q fp16 [8192][512] 8 MB
static constexpr size_t OFF_KH  = OFF_QH + 8388608;        // K fp16 [8192][512] 8 MB
static constexpr size_t OFF_VT  = OFF_KH + 8388608;        // V^T fp16 [4][8][64][2048] 8 MB
static constexpr size_t OFF_A2  = OFF_VT + 8388608;        // attn out fp16 [8192][512] 8 MB

// ---------------- convert x: fp32 -> fp16, 8 elems/thread ----------------
__global__ void k_cvt_x(const float* __restrict__ x, f16* __restrict__ xh) {
  int i = blockIdx.x * blockDim.x + threadIdx.x;          // 524288 threads exactly
  const float4* p = (const float4*)x + (size_t)i * 2;
  float4 a = p[0], b = p[1];
  f16x8 o = { (f16)a.x, (f16)a.y, (f16)a.z, (f16)a.w,
              (f16)b.x, (f16)b.y, (f16)b.z, (f16)b.w };
  *((f16x8*)xh + i) = o;
}

// ---------- transpose+convert 512x512 weight: wt[n][k] = (f16)w[k][n] ----------
__global__ void k_cvt_wt(const float* __restrict__ w, f16* __restrict__ wt) {
  __shared__ float tile[32][33];                          // +1 pad: no bank conflicts
  int tx = threadIdx.x & 31, ty = threadIdx.x >> 5;       // 32 x 8
  int bx = blockIdx.x, by = blockIdx.y;                   // bx: n-tile, by: k-tile
#pragma unroll
  for (int i = 0; i < 32; i += 8)
    tile[ty + i][tx] = w[(size_t)(by * 32 + ty + i) * 512 + bx * 32 + tx];
  __syncthreads();
#pragma unroll
  for (int i = 0; i < 32; i += 8)
    wt[(size_t)(bx * 32 + ty + i) * 512 + by * 32 + tx] = (f16)tile[tx][ty + i];
}

// ---------------- 128x128-tile fp16 MFMA GEMM, K=512, BK=64 ----------------
// A: [M][512] fp16 row-major.  Bt: [512][512] fp16 = B^T (row n holds column n of B).
// MODE 0: C fp16 row-major [M][512]
// MODE 1: C = V^T fp16 [b][h][d][n]  (scatter-transposed epilogue)
// MODE 2: C fp32 row-major + bias
template <int MODE>
__global__ __launch_bounds__(256, 2)
void k_gemm(const f16* __restrict__ A, const f16* __restrict__ Bt,
            void* __restrict__ Cout, const float* __restrict__ bias) {
  __shared__ __align__(16) f16 sA[128 * 64];
  __shared__ __align__(16) f16 sB[128 * 64];
  const int t = threadIdx.x;
  const int lane = t & 63, w = t >> 6;
  const int wr = w >> 1, wc = w & 1;
  const int l15 = lane & 15, l4 = lane >> 4;
  const int row0 = blockIdx.y * 128;
  const int col0 = blockIdx.x * 128;

  f32x4 acc[4][4] = {};
  uint4 ra[4], rb[4];

  auto load_tiles = [&](int kt) {
#pragma unroll
    for (int p = 0; p < 4; ++p) {
      int lb = p * 4096 + t * 16;         // logical byte in 16KB tile
      int r = lb >> 7, cb = lb & 127;     // row 0..127, col-byte
      ra[p] = *(const uint4*)((const char*)A + ((size_t)(row0 + r) * 512 + kt) * 2 + cb);
      rb[p] = *(const uint4*)((const char*)Bt + ((size_t)(col0 + r) * 512 + kt) * 2 + cb);
    }
  };

  load_tiles(0);
  for (int kt = 0; kt < 512; kt += 64) {
    __syncthreads();                       // previous tile fully consumed
#pragma unroll
    for (int p = 0; p < 4; ++p) {
      int lb = p * 4096 + t * 16;
      int pb = lb ^ (((lb >> 7) & 7) << 4);  // XOR swizzle (G4 / T2)
      *(uint4*)((char*)sA + pb) = ra[p];
      *(uint4*)((char*)sB + pb) = rb[p];
    }
    if (kt < 448) load_tiles(kt + 64);     // prefetch next tile (2-phase pipeline)
    __syncthreads();
#pragma unroll
    for (int kb = 0; kb < 2; ++kb) {
      f16x8 af[4], bf[4];
#pragma unroll
      for (int m = 0; m < 4; ++m) {
        int r = wr * 64 + m * 16 + l15;
        int lb = r * 128 + kb * 64 + l4 * 16;
        af[m] = *(const f16x8*)((const char*)sA + (lb ^ ((r & 7) << 4)));
      }
#pragma unroll
      for (int n = 0; n < 4; ++n) {
        int r = wc * 64 + n * 16 + l15;
        int lb = r * 128 + kb * 64 + l4 * 16;
        bf[n] = *(const f16x8*)((const char*)sB + (lb ^ ((r & 7) << 4)));
      }
#pragma unroll
      for (int m = 0; m < 4; ++m)
#pragma unroll
        for (int n = 0; n < 4; ++n)
          acc[m][n] = MFMA16(af[m], bf[n], acc[m][n]);
    }
  }

  // epilogue; C frag layout: col = lane&15, row = (lane>>4)*4 + reg
#pragma unroll
  for (int m = 0; m < 4; ++m) {
#pragma unroll
    for (int n = 0; n < 4; ++n) {
      int gr = row0 + wr * 64 + m * 16 + l4 * 4;   // row of reg 0
      int gc = col0 + wc * 64 + n * 16 + l15;
      if (MODE == 0) {
        f16* C = (f16*)Cout;
#pragma unroll
        for (int rr = 0; rr < 4; ++rr)
          C[(size_t)(gr + rr) * 512 + gc] = (f16)acc[m][n][rr];
      } else if (MODE == 1) {
        f16* C = (f16*)Cout;
        int hh = gc >> 6, dd = gc & 63;
        int bb = gr >> 11, ns = gr & 2047;         // 4 consecutive n, 8B-aligned
        union { uint2 u2; f16 v[4]; } pk;
#pragma unroll
        for (int rr = 0; rr < 4; ++rr) pk.v[rr] = (f16)acc[m][n][rr];
        *(uint2*)(C + (size_t)((bb * 8 + hh) * 64 + dd) * 2048 + ns) = pk.u2;
      } else {
        float* C = (float*)Cout;
        float bv = bias[gc];
#pragma unroll
        for (int rr = 0; rr < 4; ++rr)
          C[(size_t)(gr + rr) * 512 + gc] = acc[m][n][rr] + bv;
      }
    }
  }
}

// ---------------- flash attention, fp16 MFMA, online softmax ----------------
// Q,K: [8192][512] fp16 (head slice cols h*64..).  Vt: [b][h][64][2048] fp16.
// Block: 256 thr = 4 waves; each wave owns 16 q rows; QBLK=64, KVBLK=64.
__global__ __launch_bounds__(256, 2)
void k_attn(const f16* __restrict__ Q, const f16* __restrict__ K,
            const f16* __restrict__ Vt, const int* __restrict__ mask_k,
            const int* __restrict__ mask_q, f16* __restrict__ A2) {
  __shared__ __align__(16) f16 sK[64 * 64];   // [j][d], swizzled
  __shared__ __align__(16) f16 sV[64 * 64];   // [d][j], swizzled
  __shared__ __align__(16) f16 sP[4][16][72]; // per-wave P, padded stride
  const int t = threadIdx.x, lane = t & 63, w = t >> 6;
  const int l15 = lane & 15, l4 = lane >> 4;
  const int bh = blockIdx.y, b = bh >> 3, h = bh & 7;
  const int q0 = blockIdx.x * 64 + w * 16;    // this wave's q-row base

  // Q A-fragments: row = lane&15, k = (lane>>4)*8 (+32 for second k-block)
  f16x8 qa[2];
  {
    const f16* qb = Q + (size_t)(b * 2048 + q0 + l15) * 512 + h * 64 + l4 * 8;
    qa[0] = *(const f16x8*)qb;
    qa[1] = *(const f16x8*)(qb + 32);
  }
  int mqi[4];
#pragma unroll
  for (int rr = 0; rr < 4; ++rr)
    mqi[rr] = mask_q[b * 2048 + q0 + l4 * 4 + rr];   // C-layout rows

  float mrun[4] = {-1e30f, -1e30f, -1e30f, -1e30f};
  float lrun[4] = {0.f, 0.f, 0.f, 0.f};
  f32x4 o[4] = {};

  for (int kv = 0; kv < 2048; kv += 64) {
    __syncthreads();                         // prior iteration done with sK/sV
#pragma unroll
    for (int p = 0; p < 2; ++p) {            // stage K and V^T tiles (8KB each)
      int lb = p * 4096 + t * 16;
      int r = lb >> 7, cb = lb & 127;
      int pb = lb ^ ((r & 7) << 4);
      uint4 vk = *(const uint4*)((const char*)K +
                   ((size_t)(b * 2048 + kv + r) * 512 + h * 64) * 2 + cb);
      *(uint4*)((char*)sK + pb) = vk;
      uint4 vv = *(const uint4*)((const char*)Vt +
                   ((size_t)((b * 8 + h) * 64 + r) * 2048 + kv) * 2 + cb);
      *(uint4*)((char*)sV + pb) = vv;
    }
    __syncthreads();

    // S = Q K^T  (16 x 64 per wave)
    f32x4 s[4];
#pragma unroll
    for (int jf = 0; jf < 4; ++jf) {
      int r = jf * 16 + l15;
      int base = r * 128 + l4 * 16;
      f16x8 b0 = *(const f16x8*)((const char*)sK + (base ^ ((r & 7) << 4)));
      f16x8 b1 = *(const f16x8*)((const char*)sK + ((base + 64) ^ ((r & 7) << 4)));
      f32x4 z = {};
      z = MFMA16(qa[0], b0, z);
      z = MFMA16(qa[1], b1, z);
      s[jf] = z;
    }
    // masks + scale.  col j = jf*16 + (lane&15), row = (lane>>4)*4 + rr
    int mk[4];
#pragma unroll
    for (int jf = 0; jf < 4; ++jf)
      mk[jf] = mask_k[b * 2048 + kv + jf * 16 + l15];
    float pm[4];
#pragma unroll
    for (int rr = 0; rr < 4; ++rr) {
      float mx = -1e30f;
#pragma unroll
      for (int jf = 0; jf < 4; ++jf) {
        float sv = s[jf][rr] * 0.125f;
        sv = mqi[rr] ? (mk[jf] ? sv : -1e30f) : 0.0f;  // ref mask semantics
        s[jf][rr] = sv;
        mx = fmaxf(mx, sv);
      }
      pm[rr] = mx;
    }
#pragma unroll
    for (int x = 1; x < 16; x <<= 1)
#pragma unroll
      for (int rr = 0; rr < 4; ++rr)
        pm[rr] = fmaxf(pm[rr], __shfl_xor(pm[rr], x, 64));

    float fac[4], psum[4];
#pragma unroll
    for (int rr = 0; rr < 4; ++rr) {
      float mn = fmaxf(mrun[rr], pm[rr]);
      fac[rr] = __expf(mrun[rr] - mn);
      mrun[rr] = mn;
      float ps = 0.f;
#pragma unroll
      for (int jf = 0; jf < 4; ++jf) {
        float p = __expf(s[jf][rr] - mn);
        s[jf][rr] = p;
        ps += p;
      }
      psum[rr] = ps;
    }
#pragma unroll
    for (int x = 1; x < 16; x <<= 1)
#pragma unroll
      for (int rr = 0; rr < 4; ++rr)
        psum[rr] += __shfl_xor(psum[rr], x, 64);
#pragma unroll
    for (int rr = 0; rr < 4; ++rr) {
      lrun[rr] = lrun[rr] * fac[rr] + psum[rr];
#pragma unroll
      for (int df = 0; df < 4; ++df) o[df][rr] *= fac[rr];
    }
    // P -> LDS (per-wave region), then consumed by same wave's MFMA
#pragma unroll
    for (int jf = 0; jf < 4; ++jf)
#pragma unroll
      for (int rr = 0; rr < 4; ++rr)
        sP[w][l4 * 4 + rr][jf * 16 + l15] = (f16)s[jf][rr];
    __syncthreads();   // conservatively order P writes before P frag reads

    // O += P V   (A-frag rows = lane&15 from sP; B-frag cols = d from sV)
#pragma unroll
    for (int kb = 0; kb < 2; ++kb) {
      f16x8 pa = *(const f16x8*)&sP[w][l15][kb * 32 + l4 * 8];
#pragma unroll
      for (int df = 0; df < 4; ++df) {
        int r = df * 16 + l15;
        int base = r * 128 + kb * 64 + l4 * 16;
        f16x8 bv = *(const f16x8*)((const char*)sV + (base ^ ((r & 7) << 4)));
        o[df] = MFMA16(pa, bv, o[df]);
      }
    }
  }

  // finalize: divide by softmax denom, write fp16 attn-out [8192][512]
  float inv[4];
#pragma unroll
  for (int rr = 0; rr < 4; ++rr) inv[rr] = 1.0f / lrun[rr];
#pragma unroll
  for (int df = 0; df < 4; ++df)
#pragma unroll
    for (int rr = 0; rr < 4; ++rr)
      A2[(size_t)(b * 2048 + q0 + l4 * 4 + rr) * 512 + h * 64 + df * 16 + l15] =
          (f16)(o[df][rr] * inv[rr]);
}

extern "C" void kernel_launch(void* const* d_in, const int* in_sizes, int n_in,
                              void* d_out, int out_size, void* d_ws, size_t ws_size,
                              hipStream_t stream) {
  (void)in_sizes; (void)n_in; (void)out_size; (void)ws_size;
  const float* x   = (const float*)d_in[0];
  const float* Wq  = (const float*)d_in[1];
  const float* Wk  = (const float*)d_in[2];
  const float* Wv  = (const float*)d_in[3];
  const float* Wo  = (const float*)d_in[4];
  const float* bo  = (const float*)d_in[5];
  const int* mask_k = (const int*)d_in[6];
  const int* mask_q = (const int*)d_in[7];
  float* out = (float*)d_out;
  char* ws = (char*)d_ws;

  f16* Xh  = (f16*)(ws + OFF_XH);
  f16* Wqt = (f16*)(ws + OFF_WQT);
  f16* Wkt = (f16*)(ws + OFF_WKT);
  f16* Wvt = (f16*)(ws + OFF_WVT);
  f16* Wot = (f16*)(ws + OFF_WOT);
  f16* Qh  = (f16*)(ws + OFF_QH);
  f16* Kh  = (f16*)(ws + OFF_KH);
  f16* Vt  = (f16*)(ws + OFF_VT);
  f16* A2  = (f16*)(ws + OFF_A2);

  k_cvt_x<<<2048, 256, 0, stream>>>(x, Xh);
  k_cvt_wt<<<dim3(16, 16), 256, 0, stream>>>(Wq, Wqt);
  k_cvt_wt<<<dim3(16, 16), 256, 0, stream>>>(Wk, Wkt);
  k_cvt_wt<<<dim3(16, 16), 256, 0, stream>>>(Wv, Wvt);
  k_cvt_wt<<<dim3(16, 16), 256, 0, stream>>>(Wo, Wot);

  k_gemm<0><<<dim3(4, 64), 256, 0, stream>>>(Xh, Wqt, (void*)Qh, nullptr);
  k_gemm<0><<<dim3(4, 64), 256, 0, stream>>>(Xh, Wkt, (void*)Kh, nullptr);
  k_gemm<1><<<dim3(4, 64), 256, 0, stream>>>(Xh, Wvt, (void*)Vt, nullptr);

  k_attn<<<dim3(32, 32), 256, 0, stream>>>(Qh, Kh, Vt, mask_k, mask_q, A2);

  k_gemm<2><<<dim3(4, 64), 256, 0, stream>>>(A2, Wot, (void*)out, bo);
}